// Round 4
// baseline (144.034 us; speedup 1.0000x reference)
//
#include <hip/hip_runtime.h>

// FWHT of 2^24 float32, output scaled by 1/2^24. Two kernels (cooperative
// fusion FAILED in R3: silent launch rejection -> zero output; reverted).
//   Pass 1: bits 0-13 (contiguous 16K chunks, 64 KB LDS, reg-blocked 5+5+4).
//     v6: G2 re-paired to own f = {2t, 2t+1} -> ds_read_b64 + float2 global
//     stores (512 B segments, half the instructions). G0/G1 unchanged.
//   Pass 2: bits 14-23 over the (r=1024, c=16384) view.
//     v1 16col/64B: 2.85 TB/s; v2 32col/128B: ~3.3; v3 256B: NULL;
//     v4 XCD-gang: NULL. -> segment size / page locality are NOT the
//     limiter. v6 (this): column-PAIR ownership, all global+LDS traffic
//     float2 (8 B/lane): half the VMEM and LDS instruction count at equal
//     coverage. Theory: scalar 4 B/lane access (G13: ~2-2.5x tax) is the
//     residual 2x vs the 6.3 TB/s copy ceiling.

#define CHUNK_LOG2 14           // pass-1 chunk = 16384 elements = 64 KB LDS
#define CHUNK (1 << CHUNK_LOG2)

// Pass-1 LDS swizzle: flips addr bits 2-4 with ((e>>5 ^ e>>7)&7), keeping
// bits 0-1 -> preserves float2/float4 alignment and even-pair adjacency.
// All pass-1 LDS phases land at or near the bank floor (free per m136).
static __device__ __forceinline__ int swz(int e) {
  return e ^ ((((e >> 5) ^ (e >> 7)) & 7) << 2);
}

static __device__ __forceinline__ void fwht32(float* v) {
#pragma unroll
  for (int h = 1; h < 32; h <<= 1) {
#pragma unroll
    for (int g = 0; g < 32; g += 2 * h) {
#pragma unroll
      for (int k = 0; k < h; ++k) {
        float a = v[g + k], b = v[g + k + h];
        v[g + k] = a + b;
        v[g + k + h] = a - b;
      }
    }
  }
}

static __device__ __forceinline__ void fwht32_2(float2* v) {
#pragma unroll
  for (int h = 1; h < 32; h <<= 1) {
#pragma unroll
    for (int g = 0; g < 32; g += 2 * h) {
#pragma unroll
      for (int k = 0; k < h; ++k) {
        float2 a = v[g + k], b = v[g + k + h];
        v[g + k] = make_float2(a.x + b.x, a.y + b.y);
        v[g + k + h] = make_float2(a.x - b.x, a.y - b.y);
      }
    }
  }
}

static __device__ __forceinline__ void fwht16_2(float2* v) {
#pragma unroll
  for (int h = 1; h < 16; h <<= 1) {
#pragma unroll
    for (int g = 0; g < 16; g += 2 * h) {
#pragma unroll
      for (int k = 0; k < h; ++k) {
        float2 a = v[g + k], b = v[g + k + h];
        v[g + k] = make_float2(a.x + b.x, a.y + b.y);
        v[g + k + h] = make_float2(a.x - b.x, a.y - b.y);
      }
    }
  }
}

// Pass 1: per-block contiguous chunk of 16384 floats; stages over bits 0-13.
__global__ __launch_bounds__(512) void fwht_pass1(const float* __restrict__ in,
                                                  float* __restrict__ out) {
  __shared__ float lds[CHUNK];
  const int t = threadIdx.x;                 // [0, 512)
  const int base = (int)blockIdx.x << CHUNK_LOG2;
  float v[32];

  // Group 0: thread owns contiguous e = 32t .. 32t+31 (bits 0-4). float4.
  const float4* g4 = reinterpret_cast<const float4*>(in + base) + t * 8;
#pragma unroll
  for (int q = 0; q < 8; ++q) {
    float4 f = g4[q];
    v[4 * q + 0] = f.x; v[4 * q + 1] = f.y;
    v[4 * q + 2] = f.z; v[4 * q + 3] = f.w;
  }
  fwht32(v);  // bits 0-4
#pragma unroll
  for (int q = 0; q < 8; ++q) {
    int e = t * 32 + q * 4;
    *reinterpret_cast<float4*>(&lds[swz(e)]) =
        make_float4(v[4 * q], v[4 * q + 1], v[4 * q + 2], v[4 * q + 3]);
  }
  __syncthreads();

  // Group 1: thread owns e = lo + (j<<5) + (hi<<10), j = 0..31 (bits 5-9).
  const int lo = t & 31, hi = t >> 5;        // hi in [0,16)
#pragma unroll
  for (int j = 0; j < 32; ++j) v[j] = lds[swz(lo + (j << 5) + (hi << 10))];
  fwht32(v);  // bits 5-9
#pragma unroll
  for (int j = 0; j < 32; ++j) lds[swz(lo + (j << 5) + (hi << 10))] = v[j];
  __syncthreads();

  // Group 2 (v6): thread owns f = {2t, 2t+1}, jr = 0..15 (bits 10-13).
  // swz keeps even pairs adjacent -> ds_read_b64; stores are float2 ->
  // 128 consecutive floats per wave instruction = 512 B segments.
  float2 w[16];
#pragma unroll
  for (int jr = 0; jr < 16; ++jr)
    w[jr] = *reinterpret_cast<const float2*>(&lds[swz(2 * t + (jr << 10))]);
  fwht16_2(w);  // bits 10-13 for both owned columns
#pragma unroll
  for (int jr = 0; jr < 16; ++jr)
    *reinterpret_cast<float2*>(&out[base + 2 * t + (jr << 10)]) = w[jr];
}

// Pass 2 v6: view i = r*16384 + c, r in [0,1024), c in [0,16384).
// Block owns a 1024-row x 32-col tile (grid 512, 512 threads). Thread t:
// cp = t&15 (column PAIR, cols 2cp/2cp+1 of the tile), rgrp = t>>4 in
// [0,32). All global and LDS traffic is float2.
//   A: v[j] = rows rgrp*32+j (j=0..31) -> fwht32_2 = global bits 14-18
//      (j is the LOW 5 bits of r; bit14 of i = bit0 of r).
//   Exchange via 64 KB float2 LDS in two 512-row halves (3 barriers):
//      half h holds rows [512h, 512h+512); writers = threads with
//      rgrp<16 (h=0) / rgrp>=16 (h=1) storing lds2[(r - 512h)*16 + cp];
//      readers (all threads) pull u[j] = row rgrp+32j for the half's j's.
//   B: fwht32_2(u) = global bits 19-23; store u[j] to row rgrp+32j.
// LDS: addr stride per row = 16 float2 = 128 B -> bank-pair = cp; 4 lanes
// per bank-pair = the ds_*_b64 floor -> conflict-free.
// In-place safe: all loads precede first barrier; stores follow last LDS
// read; blocks own disjoint 32-col ranges.
__global__ __launch_bounds__(512, 4) void fwht_pass2(float* __restrict__ io) {
  __shared__ float2 lds2[512 * 16];          // 64 KB
  const int t = threadIdx.x;                 // [0, 512)
  const int cp = t & 15, rgrp = t >> 4;      // rgrp in [0,32)
  float2* io2 = reinterpret_cast<float2*>(io);
  const int c2 = (int)blockIdx.x * 16 + cp;  // float2 column index
  float2 v[32], u[32];

  // A: v[j] = float2 at (row rgrp*32+j, col-pair c2). Row stride in float2
  // units = 8192. Wave = 4 rows x 128 B contiguous per instruction.
#pragma unroll
  for (int j = 0; j < 32; ++j)
    v[j] = io2[(rgrp * 32 + j) * 8192 + c2];
  fwht32_2(v);  // bits 14-18

  // Half 0: rows [0,512) -> writers rgrp < 16 (wave-uniform predicate).
  if (rgrp < 16) {
#pragma unroll
    for (int j = 0; j < 32; ++j)
      lds2[(rgrp * 32 + j) * 16 + cp] = v[j];
  }
  __syncthreads();
  // u[j] = row rgrp + 32j; rows < 512 <=> j in [0,16).
#pragma unroll
  for (int j = 0; j < 16; ++j)
    u[j] = lds2[(rgrp + 32 * j) * 16 + cp];
  __syncthreads();

  // Half 1: rows [512,1024) -> writers rgrp >= 16; lds row = r - 512.
  if (rgrp >= 16) {
#pragma unroll
    for (int j = 0; j < 32; ++j)
      lds2[((rgrp - 16) * 32 + j) * 16 + cp] = v[j];
  }
  __syncthreads();
  // j in [16,32): r = rgrp + 32j, r - 512 = rgrp + 32(j-16).
#pragma unroll
  for (int j = 0; j < 16; ++j)
    u[16 + j] = lds2[(rgrp + 32 * j) * 16 + cp];

  fwht32_2(u);  // bits 19-23
  const float s = 1.0f / 16777216.0f;
#pragma unroll
  for (int j = 0; j < 32; ++j) {
    float2 r = u[j];
    r.x *= s; r.y *= s;
    io2[(rgrp + 32 * j) * 8192 + c2] = r;
  }
}

extern "C" void kernel_launch(void* const* d_in, const int* in_sizes, int n_in,
                              void* d_out, int out_size, void* d_ws, size_t ws_size,
                              hipStream_t stream) {
  const float* in = (const float*)d_in[0];
  float* out = (float*)d_out;
  // N = 2^24: pass 1 -> d_out, pass 2 in-place on d_out.
  fwht_pass1<<<1024, 512, 0, stream>>>(in, out);
  fwht_pass2<<<512, 512, 0, stream>>>(out);
}